// Round 1
// baseline (568.793 us; speedup 1.0000x reference)
//
#include <hip/hip_runtime.h>
#include <hip/hip_bf16.h>

// VQEmbedding straight-through forward:
//   z_e_x: [B=64, C=256, H=32, W=32] fp32, codebook: [K=1024, C=256] fp32
//   out: (z_q_x, z_q_x) both [B,C,H,W] fp32, concatenated flat.
// argmin_k ||x - c_k||^2 == argmin_k (||c_k||^2 - 2 x.c_k)  (||x||^2 constant per pixel)

#define C_DIM 256
#define HW    1024
#define K_CODES 1024
#define OUT_OFF 16777216   // 64*256*32*32

__global__ __launch_bounds__(256) void vq_cnorm_kernel(const float* __restrict__ cb,
                                                       float* __restrict__ cnorm) {
    int k = blockIdx.x * 256 + threadIdx.x;
    if (k >= K_CODES) return;
    const float4* row = reinterpret_cast<const float4*>(cb + (size_t)k * C_DIM);
    float s = 0.f;
#pragma unroll 8
    for (int u = 0; u < C_DIM / 4; ++u) {
        float4 v = row[u];
        s += v.x * v.x + v.y * v.y + v.z * v.z + v.w * v.w;
    }
    cnorm[k] = s;
}

// Block: 64 pixels (one contiguous hw-span of one batch image) x all 1024 codes.
// 256 threads: tx = t&15 (code dim), ty = t>>4 (pixel dim). 4x4 micro-tile/thread.
__global__ __launch_bounds__(256, 4) void vq_main_kernel(const float* __restrict__ z,
                                                         const float* __restrict__ cb,
                                                         const float* __restrict__ cnorm,
                                                         float* __restrict__ out) {
    __shared__ float Xs[64][64];   // [c][px]  16 KB, conflict-free
    __shared__ float Bs[64][68];   // [k][c]   17.4 KB, 68*4=272B rows keep 16B align
    __shared__ float cns[K_CODES]; // 4 KB
    __shared__ int   idxs[64];

    const int t  = threadIdx.x;
    const int tx = t & 15;
    const int ty = t >> 4;
    const int b   = blockIdx.x >> 4;
    const int hw0 = (blockIdx.x & 15) << 6;
    const size_t zbase = (size_t)b * (C_DIM * HW) + hw0;

#pragma unroll
    for (int r = 0; r < 4; ++r) cns[t + 256 * r] = cnorm[t + 256 * r];

    float best[4];
    int   bidx[4];
#pragma unroll
    for (int i = 0; i < 4; ++i) { best[i] = 3.4e38f; bidx[i] = 0; }

    for (int kt = 0; kt < 16; ++kt) {
        float acc[4][4];
#pragma unroll
        for (int i = 0; i < 4; ++i)
#pragma unroll
            for (int j = 0; j < 4; ++j) acc[i][j] = 0.f;

        for (int cc = 0; cc < 4; ++cc) {
            const int c0g = cc * 64;
            __syncthreads();   // previous chunk's readers done before overwrite
#pragma unroll
            for (int r = 0; r < 4; ++r) {
                // X tile: load float4 along pixel dim, store [c][px]
                int c   = (t >> 4) + 16 * r;
                int px4 = (t & 15) * 4;
                *reinterpret_cast<float4*>(&Xs[c][px4]) =
                    *reinterpret_cast<const float4*>(&z[zbase + (size_t)(c0g + c) * HW + px4]);
                // B tile: load float4 along channel dim, store [k][c]
                int k  = (t >> 4) + 16 * r;
                int c4 = (t & 15) * 4;
                *reinterpret_cast<float4*>(&Bs[k][c4]) =
                    *reinterpret_cast<const float4*>(&cb[(size_t)(kt * 64 + k) * C_DIM + c0g + c4]);
            }
            __syncthreads();

#pragma unroll
            for (int c0 = 0; c0 < 64; c0 += 4) {
                float4 xv[4], bv[4];
#pragma unroll
                for (int s = 0; s < 4; ++s)
                    xv[s] = *reinterpret_cast<const float4*>(&Xs[c0 + s][4 * ty]);
#pragma unroll
                for (int j = 0; j < 4; ++j)
                    bv[j] = *reinterpret_cast<const float4*>(&Bs[16 * j + tx][c0]);
#pragma unroll
                for (int i = 0; i < 4; ++i) {
#pragma unroll
                    for (int j = 0; j < 4; ++j) {
                        float xi0 = (i == 0) ? xv[0].x : (i == 1) ? xv[0].y : (i == 2) ? xv[0].z : xv[0].w;
                        float xi1 = (i == 0) ? xv[1].x : (i == 1) ? xv[1].y : (i == 2) ? xv[1].z : xv[1].w;
                        float xi2 = (i == 0) ? xv[2].x : (i == 1) ? xv[2].y : (i == 2) ? xv[2].z : xv[2].w;
                        float xi3 = (i == 0) ? xv[3].x : (i == 1) ? xv[3].y : (i == 2) ? xv[3].z : xv[3].w;
                        acc[i][j] = fmaf(xi0, bv[j].x,
                                    fmaf(xi1, bv[j].y,
                                    fmaf(xi2, bv[j].z,
                                    fmaf(xi3, bv[j].w, acc[i][j]))));
                    }
                }
            }
        }

        // dist = ||c||^2 - 2 x.c ; running per-pixel argmin (codes ascending in j,kt)
#pragma unroll
        for (int j = 0; j < 4; ++j) {
            int kg = kt * 64 + 16 * j + tx;
            float cnv = cns[kg];
#pragma unroll
            for (int i = 0; i < 4; ++i) {
                float d = cnv - 2.f * acc[i][j];
                if (d < best[i]) { best[i] = d; bidx[i] = kg; }
            }
        }
    }

    // reduce across the 16 tx-lanes sharing each pixel group (lowest-index tie-break)
#pragma unroll
    for (int i = 0; i < 4; ++i) {
#pragma unroll
        for (int off = 8; off >= 1; off >>= 1) {
            float od = __shfl_xor(best[i], off, 16);
            int   oi = __shfl_xor(bidx[i], off, 16);
            if (od < best[i] || (od == best[i] && oi < bidx[i])) { best[i] = od; bidx[i] = oi; }
        }
        if (tx == 0) idxs[4 * ty + i] = bidx[i];
    }
    __syncthreads();

    // gather: out[b, c, hw0+px] = codebook[idx[px]][c], written twice
    const int px = t & 63;
    const int c0 = t >> 6;
    const int code = idxs[px];
    const float* crow = cb + (size_t)code * C_DIM;
    const size_t obase = (size_t)b * (C_DIM * HW) + hw0 + px;
#pragma unroll 4
    for (int c = c0; c < C_DIM; c += 4) {
        float v = crow[c];
        out[obase + (size_t)c * HW] = v;
        out[obase + (size_t)c * HW + OUT_OFF] = v;
    }
}

extern "C" void kernel_launch(void* const* d_in, const int* in_sizes, int n_in,
                              void* d_out, int out_size, void* d_ws, size_t ws_size,
                              hipStream_t stream) {
    const float* z  = (const float*)d_in[0];
    const float* cb = (const float*)d_in[1];
    float* out = (float*)d_out;
    float* cnorm = (float*)d_ws;   // 1024 floats

    vq_cnorm_kernel<<<K_CODES / 256, 256, 0, stream>>>(cb, cnorm);
    vq_main_kernel<<<1024, 256, 0, stream>>>(z, cb, cnorm, out);
}